// Round 8
// baseline (33.531 us; speedup 1.0000x reference)
//
#include <hip/hip_runtime.h>

typedef __attribute__((ext_vector_type(8))) _Float16 half8;
typedef __attribute__((ext_vector_type(4))) float f32x4;

// ---- constants from the reference ----
#define COS_M 0.98006657784124163f
#define SIN_M 0.19866933079506122f
#define TH_C  (-0.98006657784124163f)
#define MM_C  0.039733866159012244f
#define S_OVER_TEMP (10.0f / 0.07f)

// monotone-in-c transform: c -> S*phi(c)/TEMP (loss invariant to stabilizer
// choice, so xform(rowmax * invn) works as the log-sum-exp stabilizer)
__device__ inline float xform(float c) {
  float s2 = fmaxf(1.0f - c * c, 0.0f);
  float sn = sqrtf(s2);
  float phi = c * COS_M - sn * SIN_M;
  float out = (c - TH_C > 0.0f) ? phi : (c - MM_C);
  return out * S_OVER_TEMP;
}

// ---- K2': fused normalize + G = norm(F)*norm(F)^T -> f16, + row-stat partials
// G[i,j] = (f_i . f_j) * invn_i * invn_j. Stage RAW features f32->f16 into LDS,
// row sumsq during staging, scale in epilogue. Additionally each wave exports
// per-row partial sumsq/max over its 64 cols (pre-f16 f32 values) to global:
// ssp/mxp[(bn*2+wc)*2048 + globalrow] -- written by exactly one wave, no init.
__global__ __launch_bounds__(256) void k_gemm_norm(const float* __restrict__ feats,
                                                   _Float16* __restrict__ Gh,
                                                   float* __restrict__ ssp,
                                                   float* __restrict__ mxp) {
  __shared__ alignas(16) _Float16 la[128 * 200];  // stride 200: 2-way alias = free
  __shared__ alignas(16) _Float16 lb[128 * 200];
  __shared__ float rsA[128], rsBs[128];
  const int bm = blockIdx.x, bn = blockIdx.y;
  const int t = threadIdx.x;
  const bool diag = (bn == bm);

  auto stage = [&](int bt, _Float16* lds, float* rs) {
    const int rr = t >> 1, h = t & 1;  // 2 threads per row, 96 floats each
    const int r = bt * 128 + rr;
    const float4* s4 =
        (const float4*)(feats + (size_t)((r & 1023) * 2 + (r >> 10)) * 192 + h * 96);
    float ss = 0.f;
    _Float16* dst = lds + rr * 200 + h * 96;
#pragma unroll
    for (int q = 0; q < 12; ++q) {
      float4 va = s4[2 * q], vb = s4[2 * q + 1];
      ss += va.x * va.x + va.y * va.y + va.z * va.z + va.w * va.w;
      ss += vb.x * vb.x + vb.y * vb.y + vb.z * vb.z + vb.w * vb.w;
      half8 o = {(_Float16)va.x, (_Float16)va.y, (_Float16)va.z, (_Float16)va.w,
                 (_Float16)vb.x, (_Float16)vb.y, (_Float16)vb.z, (_Float16)vb.w};
      *(half8*)(dst + q * 8) = o;
    }
    ss += __shfl_xor(ss, 1);  // pair (2k,2k+1): full-row sumsq
    if (h == 0) rs[rr] = rsqrtf(fmaxf(ss, 1e-24f));
  };
  stage(bm, la, rsA);
  if (!diag) stage(bn, lb, rsBs);
  __syncthreads();
  const _Float16* Bp = diag ? la : lb;
  const float* rsB = diag ? rsA : rsBs;

  const int lane = t & 63;
  const int w = t >> 6;
  const int wr = w >> 1, wc = w & 1;  // 2x2 wave grid, 64x64 each
  const int lr = lane & 15, kg = lane >> 4;

  f32x4 acc[4][4];
#pragma unroll
  for (int m = 0; m < 4; ++m)
#pragma unroll
    for (int n = 0; n < 4; ++n) acc[m][n] = (f32x4){0.f, 0.f, 0.f, 0.f};

#pragma unroll
  for (int kc = 0; kc < 6; ++kc) {  // K = 192 = 6 * 32
    half8 af[4], bf[4];
    const int koff = kc * 32 + kg * 8;
#pragma unroll
    for (int m = 0; m < 4; ++m)
      af[m] = *(const half8*)&la[(wr * 64 + m * 16 + lr) * 200 + koff];
#pragma unroll
    for (int n = 0; n < 4; ++n)
      bf[n] = *(const half8*)&Bp[(wc * 64 + n * 16 + lr) * 200 + koff];
#pragma unroll
    for (int m = 0; m < 4; ++m)
#pragma unroll
      for (int n = 0; n < 4; ++n)
        acc[m][n] = __builtin_amdgcn_mfma_f32_16x16x32_f16(af[m], bf[n], acc[m][n], 0, 0, 0);
  }

  const int rb = bm * 128 + wr * 64;
  const int cb = bn * 128 + wc * 64;
  const int grp = bn * 2 + wc;  // this wave's 64-col group (0..31)
#pragma unroll
  for (int m = 0; m < 4; ++m)
#pragma unroll
    for (int n = 0; n < 4; ++n) {
      const int r0 = rb + m * 16 + kg * 4;  // C/D: col=lane&15, row=(lane>>4)*4+e
      const int c0 = cb + n * 16 + lr;
      const float sb = rsB[wc * 64 + n * 16 + lr];
#pragma unroll
      for (int e = 0; e < 4; ++e) {  // R1-shape store (validated R4-R7)
        const float sa = rsA[wr * 64 + m * 16 + kg * 4 + e];
        Gh[(size_t)(r0 + e) * 2048 + c0] = (_Float16)(acc[m][n][e] * sa * sb);
      }
    }

  // per-row partial stats over this wave's 64 cols (normalized f32, pre-f16)
#pragma unroll
  for (int m = 0; m < 4; ++m) {
#pragma unroll
    for (int e = 0; e < 4; ++e) {
      const float sa = rsA[wr * 64 + m * 16 + kg * 4 + e];
      float s = 0.f, x = -3.4e38f;
#pragma unroll
      for (int n = 0; n < 4; ++n) {
        const float g = acc[m][n][e] * sa * rsB[wc * 64 + n * 16 + lr];
        s += g * g;
        x = fmaxf(x, g);
      }
#pragma unroll
      for (int mk = 1; mk < 16; mk <<= 1) {  // reduce across the 16 lr lanes
        s += __shfl_xor(s, mk);
        x = fmaxf(x, __shfl_xor(x, mk));
      }
      if (lr == 0) {
        const int row = rb + m * 16 + kg * 4 + e;
        ssp[grp * 2048 + row] = s;
        mxp[grp * 2048 + row] = x;
      }
    }
  }
}

// ---- K3: one-pass row loss. 4 independent waves/block (zero sync), stats from
// precomputed partials (32 broadcast loads), single butterfly for es/ps/cn.
__global__ __launch_bounds__(256) void k_rowloss(const _Float16* __restrict__ Gh,
                                                 const float* __restrict__ ssp,
                                                 const float* __restrict__ mxp,
                                                 const int* __restrict__ labels,
                                                 float* __restrict__ lossv) {
  const int w = threadIdx.x >> 6;
  const int i = blockIdx.x * 4 + w;  // this wave's row
  const int l = threadIdx.x & 63;
  const _Float16* row = Gh + (size_t)i * 2048;

  half8 v[4];
#pragma unroll
  for (int p = 0; p < 4; ++p)  // 4 independent 16B loads in flight
    v[p] = *(const half8*)&row[512 * p + 8 * l];

  // row stats: 32 partials per array, wave-uniform broadcast loads
  float ss = 0.f, mx = -3.4e38f;
#pragma unroll
  for (int q = 0; q < 32; ++q) {
    ss += ssp[q * 2048 + i];
    mx = fmaxf(mx, mxp[q * 2048 + i]);
  }
  const float invn = 1.0f / fmaxf(sqrtf(ss), 1e-12f);
  const float Mst = xform(mx * invn);  // stabilizer (loss-invariant choice)

  const int4 a0 = *(const int4*)&labels[8 * l];
  const int4 a1 = *(const int4*)&labels[8 * l + 4];
  const int4 b0 = *(const int4*)&labels[512 + 8 * l];
  const int4 b1 = *(const int4*)&labels[512 + 8 * l + 4];
  const int labs[2][8] = {{a0.x, a0.y, a0.z, a0.w, a1.x, a1.y, a1.z, a1.w},
                          {b0.x, b0.y, b0.z, b0.w, b1.x, b1.y, b1.z, b1.w}};
  const int mylab = labels[i & 1023];

  float es = 0.f, ps = 0.f, cn = 0.f;
#pragma unroll
  for (int p = 0; p < 4; ++p)
#pragma unroll
    for (int u = 0; u < 8; ++u) {
      const int j = 512 * p + 8 * l + u;
      const float lg = xform((float)v[p][u] * invn) - Mst;
      if (j != i) {
        es += expf(lg);
        if (labs[p & 1][u] == mylab) { ps += lg; cn += 1.f; }
      }
    }
#pragma unroll
  for (int o = 32; o; o >>= 1) {
    es += __shfl_xor(es, o);
    ps += __shfl_xor(ps, o);
    cn += __shfl_xor(cn, o);
  }
  if (l == 0) lossv[i] = -(ps / cn - logf(es));
}

// ---------------- K4: mean over 2048 rows -> scalar ----------------
__global__ __launch_bounds__(256) void k_final(const float* __restrict__ lossv,
                                               float* __restrict__ out) {
  const int t = threadIdx.x;
  float s = 0.f;
  for (int j = t; j < 2048; j += 256) s += lossv[j];
#pragma unroll
  for (int o = 32; o; o >>= 1) s += __shfl_down(s, o);
  __shared__ float r4[4];
  if ((t & 63) == 0) r4[t >> 6] = s;
  __syncthreads();
  if (t == 0) out[0] = (r4[0] + r4[1] + r4[2] + r4[3]) * (1.0f / 2048.0f);
}

extern "C" void kernel_launch(void* const* d_in, const int* in_sizes, int n_in,
                              void* d_out, int out_size, void* d_ws, size_t ws_size,
                              hipStream_t stream) {
  const float* feats = (const float*)d_in[0];
  const int* labels = (const int*)d_in[1];
  // d_in[2]/d_in[3] (fc_w/fc_b) are provably dead: atten == 1.0 exactly

  char* ws = (char*)d_ws;
  float* lossv = (float*)ws;                      // 2048*4      = 8 KiB
  float* ssp   = (float*)(ws + 16384);            // 32*2048*4   = 256 KiB
  float* mxp   = (float*)(ws + 16384 + 262144);   // 32*2048*4   = 256 KiB
  _Float16* Gh = (_Float16*)(ws + (1 << 20));     // 2048*2048*2 = 8 MiB

  dim3 g2(16, 16);
  k_gemm_norm<<<g2, 256, 0, stream>>>(feats, Gh, ssp, mxp);
  k_rowloss<<<512, 256, 0, stream>>>(Gh, ssp, mxp, labels, lossv);
  k_final<<<1, 256, 0, stream>>>(lossv, (float*)d_out);
}

// Round 9
// 29.904 us; speedup vs baseline: 1.1213x; 1.1213x over previous
//
#include <hip/hip_runtime.h>

typedef __attribute__((ext_vector_type(8))) _Float16 half8;
typedef __attribute__((ext_vector_type(4))) float f32x4;

// ---- constants from the reference ----
#define COS_M 0.98006657784124163f
#define SIN_M 0.19866933079506122f
#define TH_C  (-0.98006657784124163f)
#define MM_C  0.039733866159012244f
#define S_OVER_TEMP (10.0f / 0.07f)
#define LOG2E 1.44269504088896340736f
#define LN2   0.69314718055994530942f

// monotone-in-c transform: c -> S*phi(c)/TEMP (loss invariant to stabilizer
// choice, so xform(rowmax * invn) works as the log-sum-exp stabilizer)
__device__ inline float xform(float c) {
  float s2 = fmaxf(1.0f - c * c, 0.0f);
  float sn = sqrtf(s2);
  float phi = c * COS_M - sn * SIN_M;
  float out = (c - TH_C > 0.0f) ? phi : (c - MM_C);
  return out * S_OVER_TEMP;
}

// ---- K2': fused normalize + G = norm(F)*norm(F)^T -> f16 (R7-proven) --------
// G[i,j] = (f_i . f_j) * invn_i * invn_j : stage RAW features f32->f16 into
// LDS, accumulate row sumsq during staging (free), scale in the epilogue.
// 128x128 tile per block, 4 waves (2x2), each wave 64x64 = 4x4 frags of 16x16.
__global__ __launch_bounds__(256) void k_gemm_norm(const float* __restrict__ feats,
                                                   _Float16* __restrict__ Gh,
                                                   float* __restrict__ out) {
  __shared__ alignas(16) _Float16 la[128 * 200];  // stride 200: 2-way alias = free
  __shared__ alignas(16) _Float16 lb[128 * 200];
  __shared__ float rsA[128], rsBs[128];
  const int bm = blockIdx.x, bn = blockIdx.y;
  const int t = threadIdx.x;
  const bool diag = (bn == bm);
  if (bm == 0 && bn == 0 && t == 0) out[0] = 0.0f;  // stream-ordered before K3

  auto stage = [&](int bt, _Float16* lds, float* rs) {
    const int rr = t >> 1, h = t & 1;  // 2 threads per row, 96 floats each
    const int r = bt * 128 + rr;
    const float4* s4 =
        (const float4*)(feats + (size_t)((r & 1023) * 2 + (r >> 10)) * 192 + h * 96);
    float ss = 0.f;
    _Float16* dst = lds + rr * 200 + h * 96;
#pragma unroll
    for (int q = 0; q < 12; ++q) {
      float4 va = s4[2 * q], vb = s4[2 * q + 1];
      ss += va.x * va.x + va.y * va.y + va.z * va.z + va.w * va.w;
      ss += vb.x * vb.x + vb.y * vb.y + vb.z * vb.z + vb.w * vb.w;
      half8 o = {(_Float16)va.x, (_Float16)va.y, (_Float16)va.z, (_Float16)va.w,
                 (_Float16)vb.x, (_Float16)vb.y, (_Float16)vb.z, (_Float16)vb.w};
      *(half8*)(dst + q * 8) = o;
    }
    ss += __shfl_xor(ss, 1);  // pair (2k,2k+1): full-row sumsq
    if (h == 0) rs[rr] = rsqrtf(fmaxf(ss, 1e-24f));
  };
  stage(bm, la, rsA);
  if (!diag) stage(bn, lb, rsBs);
  __syncthreads();
  const _Float16* Bp = diag ? la : lb;
  const float* rsB = diag ? rsA : rsBs;

  const int lane = t & 63;
  const int w = t >> 6;
  const int wr = w >> 1, wc = w & 1;  // 2x2 wave grid, 64x64 each
  const int lr = lane & 15, kg = lane >> 4;

  f32x4 acc[4][4];
#pragma unroll
  for (int m = 0; m < 4; ++m)
#pragma unroll
    for (int n = 0; n < 4; ++n) acc[m][n] = (f32x4){0.f, 0.f, 0.f, 0.f};

#pragma unroll
  for (int kc = 0; kc < 6; ++kc) {  // K = 192 = 6 * 32
    half8 af[4], bf[4];
    const int koff = kc * 32 + kg * 8;
#pragma unroll
    for (int m = 0; m < 4; ++m)
      af[m] = *(const half8*)&la[(wr * 64 + m * 16 + lr) * 200 + koff];
#pragma unroll
    for (int n = 0; n < 4; ++n)
      bf[n] = *(const half8*)&Bp[(wc * 64 + n * 16 + lr) * 200 + koff];
#pragma unroll
    for (int m = 0; m < 4; ++m)
#pragma unroll
      for (int n = 0; n < 4; ++n)
        acc[m][n] = __builtin_amdgcn_mfma_f32_16x16x32_f16(af[m], bf[n], acc[m][n], 0, 0, 0);
  }

  const int rb = bm * 128 + wr * 64;
  const int cb = bn * 128 + wc * 64;
#pragma unroll
  for (int m = 0; m < 4; ++m)
#pragma unroll
    for (int n = 0; n < 4; ++n) {
      const int r0 = rb + m * 16 + kg * 4;  // C/D: col=lane&15, row=(lane>>4)*4+e
      const int c0 = cb + n * 16 + lr;
      const float sb = rsB[wc * 64 + n * 16 + lr];
#pragma unroll
      for (int e = 0; e < 4; ++e) {  // R1-shape store (validated R4-R8)
        const float sa = rsA[wr * 64 + m * 16 + kg * 4 + e];
        Gh[(size_t)(r0 + e) * 2048 + c0] = (_Float16)(acc[m][n][e] * sa * sb);
      }
    }
}

// ---- K3: 4 independent waves/block, one row each (R7-proven math), LDS tail
// gather + ONE atomicAdd per block (512 total). No fences, no spinning.
__global__ __launch_bounds__(256) void k_rowloss(const _Float16* __restrict__ Gh,
                                                 const int* __restrict__ labels,
                                                 float* __restrict__ out) {
  const int w = threadIdx.x >> 6;
  const int l = threadIdx.x & 63;
  const int i = blockIdx.x * 4 + w;  // this wave's row
  const _Float16* row = Gh + (size_t)i * 2048;

  half8 v[4];
#pragma unroll
  for (int p = 0; p < 4; ++p)  // 4 independent 16B loads in flight
    v[p] = *(const half8*)&row[512 * p + 8 * l];

  float gv[4][8];
#pragma unroll
  for (int p = 0; p < 4; ++p)
#pragma unroll
    for (int u = 0; u < 8; ++u) gv[p][u] = (float)v[p][u];

  float ss = 0.f, mx = -3.4e38f;
#pragma unroll
  for (int p = 0; p < 4; ++p)
#pragma unroll
    for (int u = 0; u < 8; ++u) { ss += gv[p][u] * gv[p][u]; mx = fmaxf(mx, gv[p][u]); }
#pragma unroll
  for (int o = 32; o; o >>= 1) {  // wave-wide butterfly, no LDS
    ss += __shfl_xor(ss, o);
    mx = fmaxf(mx, __shfl_xor(mx, o));
  }
  const float invn = 1.0f / fmaxf(sqrtf(ss), 1e-12f);
  const float Mst = xform(mx * invn);  // stabilizer (loss-invariant choice)

  const int4 a0 = *(const int4*)&labels[8 * l];
  const int4 a1 = *(const int4*)&labels[8 * l + 4];
  const int4 b0 = *(const int4*)&labels[512 + 8 * l];
  const int4 b1 = *(const int4*)&labels[512 + 8 * l + 4];
  const int labs[2][8] = {{a0.x, a0.y, a0.z, a0.w, a1.x, a1.y, a1.z, a1.w},
                          {b0.x, b0.y, b0.z, b0.w, b1.x, b1.y, b1.z, b1.w}};
  const int mylab = labels[i & 1023];  // wave-uniform -> scalar load

  float es = 0.f, ps = 0.f, cn = 0.f;
#pragma unroll
  for (int p = 0; p < 4; ++p)
#pragma unroll
    for (int u = 0; u < 8; ++u) {
      const int j = 512 * p + 8 * l + u;
      const float lg = xform(gv[p][u] * invn) - Mst;
      if (j != i) {
        es += exp2f(lg * LOG2E);  // exp(lg), cheaper form
        if (labs[p & 1][u] == mylab) { ps += lg; cn += 1.f; }
      }
    }
#pragma unroll
  for (int o = 32; o; o >>= 1) {
    es += __shfl_xor(es, o);
    ps += __shfl_xor(ps, o);
    cn += __shfl_xor(cn, o);
  }

  __shared__ float part[4];
  if (l == 0) part[w] = -(ps / cn - log2f(es) * LN2);
  __syncthreads();
  if (threadIdx.x == 0)
    atomicAdd(out, (part[0] + part[1] + part[2] + part[3]) * (1.0f / 2048.0f));
}

extern "C" void kernel_launch(void* const* d_in, const int* in_sizes, int n_in,
                              void* d_out, int out_size, void* d_ws, size_t ws_size,
                              hipStream_t stream) {
  const float* feats = (const float*)d_in[0];
  const int* labels = (const int*)d_in[1];
  // d_in[2]/d_in[3] (fc_w/fc_b) are provably dead: atten == 1.0 exactly

  char* ws = (char*)d_ws;
  _Float16* Gh = (_Float16*)(ws + (1 << 20));  // 2048*2048*2 = 8 MiB

  dim3 g2(16, 16);
  k_gemm_norm<<<g2, 256, 0, stream>>>(feats, Gh, (float*)d_out);
  k_rowloss<<<512, 256, 0, stream>>>(Gh, labels, (float*)d_out);
}

// Round 10
// 27.686 us; speedup vs baseline: 1.2111x; 1.0801x over previous
//
#include <hip/hip_runtime.h>

typedef __attribute__((ext_vector_type(8))) _Float16 half8;
typedef __attribute__((ext_vector_type(4))) float f32x4;

// ---- constants from the reference ----
#define COS_M 0.98006657784124163f
#define SIN_M 0.19866933079506122f
#define TH_C  (-0.98006657784124163f)
#define MM_C  0.039733866159012244f
#define S_OVER_TEMP (10.0f / 0.07f)
#define LOG2E 1.44269504088896340736f
#define LN2   0.69314718055994530942f

// monotone-in-c transform: c -> S*phi(c)/TEMP (loss invariant to stabilizer
// choice, so xform(rowmax * invn) works as the log-sum-exp stabilizer)
__device__ inline float xform(float c) {
  float s2 = fmaxf(1.0f - c * c, 0.0f);
  float sn = sqrtf(s2);
  float phi = c * COS_M - sn * SIN_M;
  float out = (c - TH_C > 0.0f) ? phi : (c - MM_C);
  return out * S_OVER_TEMP;
}

// ---- K2': fused normalize + G = norm(F)*norm(F)^T -> f16, 8 waves/block ----
// Same 128x128 tile / LDS as R7-R9 (validated math) but 512 threads -> 2
// waves/SIMD so ds_read->MFMA and staging latency overlap across waves.
// Wave grid 2x4; each wave computes a 64x32 subtile (acc 4x2 frags).
__global__ __launch_bounds__(512) void k_gemm_norm(const float* __restrict__ feats,
                                                   _Float16* __restrict__ Gh,
                                                   float* __restrict__ out) {
  __shared__ alignas(16) _Float16 la[128 * 200];  // stride 200: 2-way alias = free
  __shared__ alignas(16) _Float16 lb[128 * 200];
  __shared__ float rsA[128], rsBs[128];
  const int bm = blockIdx.x, bn = blockIdx.y;
  const int t = threadIdx.x;
  const bool diag = (bn == bm);
  if (bm == 0 && bn == 0 && t == 0) out[0] = 0.0f;  // stream-ordered before K3

  // stage one 128-row tile: 4 threads/row, 48 floats each; rowwise sumsq -> rs
  auto stage = [&](int bt, _Float16* lds, float* rs) {
    const int rr = t >> 2, h = t & 3;
    const int r = bt * 128 + rr;
    const float4* s4 =
        (const float4*)(feats + (size_t)((r & 1023) * 2 + (r >> 10)) * 192 + h * 48);
    float ss = 0.f;
    _Float16* dst = lds + rr * 200 + h * 48;
#pragma unroll
    for (int q = 0; q < 6; ++q) {
      float4 va = s4[2 * q], vb = s4[2 * q + 1];
      ss += va.x * va.x + va.y * va.y + va.z * va.z + va.w * va.w;
      ss += vb.x * vb.x + vb.y * vb.y + vb.z * vb.z + vb.w * vb.w;
      half8 o = {(_Float16)va.x, (_Float16)va.y, (_Float16)va.z, (_Float16)va.w,
                 (_Float16)vb.x, (_Float16)vb.y, (_Float16)vb.z, (_Float16)vb.w};
      *(half8*)(dst + q * 8) = o;
    }
    ss += __shfl_xor(ss, 1);  // 4-lane group = full row
    ss += __shfl_xor(ss, 2);
    if (h == 0) rs[rr] = rsqrtf(fmaxf(ss, 1e-24f));
  };
  stage(bm, la, rsA);
  if (!diag) stage(bn, lb, rsBs);
  __syncthreads();
  const _Float16* Bp = diag ? la : lb;
  const float* rsB = diag ? rsA : rsBs;

  const int lane = t & 63;
  const int w = t >> 6;          // 8 waves
  const int wr = w >> 2, wc = w & 3;  // 2x4 wave grid, 64x32 each
  const int lr = lane & 15, kg = lane >> 4;

  f32x4 acc[4][2];
#pragma unroll
  for (int m = 0; m < 4; ++m)
#pragma unroll
    for (int n = 0; n < 2; ++n) acc[m][n] = (f32x4){0.f, 0.f, 0.f, 0.f};

#pragma unroll
  for (int kc = 0; kc < 6; ++kc) {  // K = 192 = 6 * 32
    half8 af[4], bf[2];
    const int koff = kc * 32 + kg * 8;
#pragma unroll
    for (int m = 0; m < 4; ++m)
      af[m] = *(const half8*)&la[(wr * 64 + m * 16 + lr) * 200 + koff];
#pragma unroll
    for (int n = 0; n < 2; ++n)
      bf[n] = *(const half8*)&Bp[(wc * 32 + n * 16 + lr) * 200 + koff];
#pragma unroll
    for (int m = 0; m < 4; ++m)
#pragma unroll
      for (int n = 0; n < 2; ++n)
        acc[m][n] = __builtin_amdgcn_mfma_f32_16x16x32_f16(af[m], bf[n], acc[m][n], 0, 0, 0);
  }

  const int rb = bm * 128 + wr * 64;
  const int cb = bn * 128 + wc * 32;
#pragma unroll
  for (int m = 0; m < 4; ++m)
#pragma unroll
    for (int n = 0; n < 2; ++n) {
      const int r0 = rb + m * 16 + kg * 4;  // C/D: col=lane&15, row=(lane>>4)*4+e
      const int c0 = cb + n * 16 + lr;
      const float sb = rsB[wc * 32 + n * 16 + lr];
#pragma unroll
      for (int e = 0; e < 4; ++e) {  // R1-shape store (validated R4-R9)
        const float sa = rsA[wr * 64 + m * 16 + kg * 4 + e];
        Gh[(size_t)(r0 + e) * 2048 + c0] = (_Float16)(acc[m][n][e] * sa * sb);
      }
    }
}

// ---- K3: 4 independent waves/block, one row each (proven R7/R9 math), LDS
// tail gather + ONE atomicAdd per block (512 total). No fences, no spinning.
__global__ __launch_bounds__(256) void k_rowloss(const _Float16* __restrict__ Gh,
                                                 const int* __restrict__ labels,
                                                 float* __restrict__ out) {
  const int w = threadIdx.x >> 6;
  const int l = threadIdx.x & 63;
  const int i = blockIdx.x * 4 + w;  // this wave's row
  const _Float16* row = Gh + (size_t)i * 2048;

  half8 v[4];
#pragma unroll
  for (int p = 0; p < 4; ++p)  // 4 independent 16B loads in flight
    v[p] = *(const half8*)&row[512 * p + 8 * l];

  float gv[4][8];
#pragma unroll
  for (int p = 0; p < 4; ++p)
#pragma unroll
    for (int u = 0; u < 8; ++u) gv[p][u] = (float)v[p][u];

  float ss = 0.f, mx = -3.4e38f;
#pragma unroll
  for (int p = 0; p < 4; ++p)
#pragma unroll
    for (int u = 0; u < 8; ++u) { ss += gv[p][u] * gv[p][u]; mx = fmaxf(mx, gv[p][u]); }
#pragma unroll
  for (int o = 32; o; o >>= 1) {  // wave-wide butterfly, no LDS
    ss += __shfl_xor(ss, o);
    mx = fmaxf(mx, __shfl_xor(mx, o));
  }
  const float invn = 1.0f / fmaxf(sqrtf(ss), 1e-12f);
  const float Mst = xform(mx * invn);  // stabilizer (loss-invariant choice)

  const int4 a0 = *(const int4*)&labels[8 * l];
  const int4 a1 = *(const int4*)&labels[8 * l + 4];
  const int4 b0 = *(const int4*)&labels[512 + 8 * l];
  const int4 b1 = *(const int4*)&labels[512 + 8 * l + 4];
  const int labs[2][8] = {{a0.x, a0.y, a0.z, a0.w, a1.x, a1.y, a1.z, a1.w},
                          {b0.x, b0.y, b0.z, b0.w, b1.x, b1.y, b1.z, b1.w}};
  const int mylab = labels[i & 1023];  // wave-uniform -> scalar load

  float es = 0.f, ps = 0.f, cn = 0.f;
#pragma unroll
  for (int p = 0; p < 4; ++p)
#pragma unroll
    for (int u = 0; u < 8; ++u) {
      const int j = 512 * p + 8 * l + u;
      const float lg = xform(gv[p][u] * invn) - Mst;
      if (j != i) {
        es += exp2f(lg * LOG2E);  // exp(lg)
        if (labs[p & 1][u] == mylab) { ps += lg; cn += 1.f; }
      }
    }
#pragma unroll
  for (int o = 32; o; o >>= 1) {
    es += __shfl_xor(es, o);
    ps += __shfl_xor(ps, o);
    cn += __shfl_xor(cn, o);
  }

  __shared__ float part[4];
  if (l == 0) part[w] = -(ps / cn - log2f(es) * LN2);
  __syncthreads();
  if (threadIdx.x == 0)
    atomicAdd(out, (part[0] + part[1] + part[2] + part[3]) * (1.0f / 2048.0f));
}

extern "C" void kernel_launch(void* const* d_in, const int* in_sizes, int n_in,
                              void* d_out, int out_size, void* d_ws, size_t ws_size,
                              hipStream_t stream) {
  const float* feats = (const float*)d_in[0];
  const int* labels = (const int*)d_in[1];
  // d_in[2]/d_in[3] (fc_w/fc_b) are provably dead: atten == 1.0 exactly

  char* ws = (char*)d_ws;
  _Float16* Gh = (_Float16*)(ws + (1 << 20));  // 2048*2048*2 = 8 MiB

  dim3 g2(16, 16);
  k_gemm_norm<<<g2, 512, 0, stream>>>(feats, Gh, (float*)d_out);
  k_rowloss<<<512, 256, 0, stream>>>(Gh, labels, (float*)d_out);
}